// Round 9
// baseline (260.764 us; speedup 1.0000x reference)
//
#include <hip/hip_runtime.h>
#include <hip/hip_bf16.h>

// GATConv forward, eval mode.
// Inputs: x[N,64] fp32, edge_index[2,E] int32, W[64,64] fp32, b[64] fp32.
// Output: fp32 [N,64].
//
// Pipeline (5 kernels, no memset):
//   K0 k_hist   : per 8192-edge chunk LDS bucket histogram (3125 buckets of
//                 32 nodes) -> cntg[chunk][bkt] u16.
//   K1 k_tot    : one wave per bucket: lane l serial-prefixes chunks
//                 [4l,4l+4), shfl-scan across lanes, per-chunk prefix in
//                 place, bucket total -> tot[].
//   K2 k_base   : 1 block: exclusive scan of 3125 bucket totals -> base[].
//   K3 k_scatlin: blocks [0,NCH): scatter each edge to its FINAL globally
//                 bucket-sorted slab position (LDS rank counters only);
//                 consecutive chunks pinned to one XCD (avoids round-4's
//                 cross-XCD line ping-pong). blocks [NCH,...): xl = x@W+b
//                 via MFMA bf16x2 split (+ bf16 xlh), 16 tiles/block.
//   K4 k_agg    : per bucket (3125 blocks): node-sort slab edges in LDS,
//                 pad each node's segment to a multiple of 6 with dummy
//                 self-edges, then process UNIFORM 6-EDGE SLICES round-robin
//                 across 32 groups (fixed-m softmax partials are addable, so
//                 slices of one node computed by different groups just
//                 LDS-float-atomicAdd into accsh[node]) — perfect load
//                 balance vs the old per-node loop (wave time was max degree
//                 in wave). Ring-of-6 gather pipeline maintained ACROSS the
//                 group's slice stream. Softmax BRANCHLESS: m fixed to the
//                 self score ||xl_i||^2 (Cauchy-Schwarz bounds exp<=e^~30),
//                 self seeded once in fp32. 8-lane dot reduce is DPP-only.
//                 Plain __launch_bounds__(256): round 7 proved (256,8)
//                 [min waves/EU] caps VGPR=32 and spills the ring (343MB
//                 scratch traffic, 160us).
//
// ws: xl[N*64] f32 | xlh[N*64] bf16 | cntg[NCH*NBP] u16 | tot[NB] i32 |
//     base[NB+1] i32 | slab[E] u32

#define LEAKY_SLOPE 0.2f
#define BK_SHIFT 5            // 32 nodes per bucket
#define BK_NODES 32
#define CAPB 960              // bound on PADDED edges/bucket (real max ~650 + pad <=160)
#define CH 8192               // edges per chunk
#define NBP 3136              // padded bucket count (NB=3125)
#define MAXK 8                // max chunks per lane in k_tot (need ceil(208/64)=4)

typedef __attribute__((ext_vector_type(8))) short short8;   // 8 x bf16 bits
typedef __attribute__((ext_vector_type(4))) float f32x4;

struct HiLo { short hi, lo; };

__device__ __forceinline__ HiLo split2(float f) {
    HiLo r;
    unsigned u = __float_as_uint(f);
    r.hi = (short)(u >> 16);
    float fh = __uint_as_float(u & 0xFFFF0000u);
    r.lo = (short)(__float_as_uint(f - fh) >> 16);
    return r;
}

// ---------------------------------------------------------------------------
// K0 k_hist: per-chunk bucket histogram -> cntg[chunk][bkt] (u16)
__global__ __launch_bounds__(1024) void k_hist(const int* __restrict__ row,
                                               unsigned short* __restrict__ cntg,
                                               int E, int NB) {
    __shared__ int hc[NBP];
    int tid = threadIdx.x;
    for (int i = tid; i < NBP; i += 1024) hc[i] = 0;
    __syncthreads();
    int e0 = (int)blockIdx.x * CH;
    int e1 = min(E, e0 + CH);
    for (int e = e0 + tid; e < e1; e += 1024)
        atomicAdd(&hc[row[e] >> BK_SHIFT], 1);
    __syncthreads();
    unsigned short* orow = cntg + (size_t)blockIdx.x * NBP;
    for (int i = tid; i < NB; i += 1024) orow[i] = (unsigned short)hc[i];
}

// ---------------------------------------------------------------------------
// K1 k_tot: one wave per bucket. Lane l serial-prefixes its 4 contiguous
// chunks, shfl-scan combines lanes, prefix written back in place, total out.
__global__ __launch_bounds__(256) void k_tot(unsigned short* __restrict__ cntg,
                                             int* __restrict__ tot,
                                             int NB, int nch) {
    int wavegid = (((int)blockIdx.x * 256) + (int)threadIdx.x) >> 6;
    int lane = threadIdx.x & 63;
    int b = wavegid;                     // bucket handled by this wave
    if (b >= NB) return;                 // wave-uniform exit

    int K = (nch + 63) >> 6;             // chunks per lane (4 for nch=208)
    int v[MAXK];
    int s = 0;
    int c0 = lane * K;
#pragma unroll
    for (int k = 0; k < MAXK; ++k) {
        if (k < K) {
            int c = c0 + k;
            v[k] = (c < nch) ? (int)cntg[(size_t)c * NBP + b] : 0;
        }
    }
#pragma unroll
    for (int k = 0; k < MAXK; ++k) {
        if (k < K) { int t = v[k]; v[k] = s; s += t; }
    }
    int inc = s;                         // inclusive scan of lane sums
#pragma unroll
    for (int o = 1; o < 64; o <<= 1) {
        int t = __shfl_up(inc, o, 64);
        if (lane >= o) inc += t;
    }
    int exc = inc - s;                   // exclusive prefix for this lane
#pragma unroll
    for (int k = 0; k < MAXK; ++k) {
        if (k < K) {
            int c = c0 + k;
            if (c < nch)
                cntg[(size_t)c * NBP + b] = (unsigned short)(v[k] + exc);
        }
    }
    if (lane == 63) tot[b] = inc;
}

// ---------------------------------------------------------------------------
// K2 k_base: single block, exclusive scan of tot[0..NB) -> base[], base[NB]=E
__global__ __launch_bounds__(1024) void k_base(const int* __restrict__ tot,
                                               int* __restrict__ base,
                                               int NB, int E) {
    __shared__ int segsum[16];
    int tid = threadIdx.x, lane = tid & 63, wid = tid >> 6;
    int segbeg = tid * 4;
    int loc[4];
    int s = 0;
#pragma unroll
    for (int k = 0; k < 4; ++k) {
        int i = segbeg + k;
        int t = (i < NB) ? tot[i] : 0;
        loc[k] = s; s += t;
    }
    int v = s;
#pragma unroll
    for (int o = 1; o < 64; o <<= 1) {
        int t = __shfl_up(v, o, 64);
        if (lane >= o) v += t;
    }
    if (lane == 63) segsum[wid] = v;
    __syncthreads();
    int woff = 0;
#pragma unroll
    for (int w = 0; w < 16; ++w) woff += (w < wid) ? segsum[w] : 0;
    int segoff = (v - s) + woff;
#pragma unroll
    for (int k = 0; k < 4; ++k) {
        int i = segbeg + k;
        if (i < NB) base[i] = loc[k] + segoff;
    }
    if (tid == 0) base[NB] = E;
}

// ---------------------------------------------------------------------------
// K3 k_scatlin: scatter (blocks [0,nsc)) + linear MFMA (blocks after).
union SLShMem {
    struct { short wt_hi[64 * 72]; short wt_lo[64 * 72]; } lin;   // 18432 B
    struct { int pfx[NBP], pos[NBP]; } sc;                        // 25088 B
};

__global__ __launch_bounds__(1024) void k_scatlin(const float* __restrict__ x,
                                                  const float* __restrict__ W,
                                                  const float* __restrict__ b,
                                                  const int* __restrict__ row,
                                                  const int* __restrict__ col,
                                                  float* __restrict__ xl,
                                                  unsigned short* __restrict__ xlh,
                                                  const unsigned short* __restrict__ cntg,
                                                  const int* __restrict__ base,
                                                  unsigned* __restrict__ slab,
                                                  int N, int E, int NB,
                                                  int ntiles, int nsc, int nch) {
    __shared__ SLShMem sh;
    int tid = threadIdx.x;

    if ((int)blockIdx.x < nsc) {
        // ---------------------- scatter path -------------------------------
        int cb = (int)blockIdx.x;
        // consecutive chunks on the same XCD (round-robin heuristic): keeps
        // adjacent runs of each bucket region in one XCD's L2.
        int chunk = (nch % 8 == 0) ? (cb % 8) * (nch / 8) + cb / 8 : cb;

        const unsigned short* crow = cntg + (size_t)chunk * NBP;
        for (int i = tid; i < NB; i += 1024) {
            sh.sc.pfx[i] = base[i] + (int)crow[i];
            sh.sc.pos[i] = 0;
        }
        __syncthreads();

        int e0 = chunk * CH;
        int e1 = min(E, e0 + CH);
        for (int e = e0 + tid; e < e1; e += 1024) {
            int r = row[e], c = col[e];
            int bkt = r >> BK_SHIFT;
            int rank = atomicAdd(&sh.sc.pos[bkt], 1);
            slab[sh.sc.pfx[bkt] + rank] =
                ((unsigned)(r & (BK_NODES - 1)) << 17) | (unsigned)c;
        }
    } else {
        // ------------------------- linear path (MFMA) ----------------------
        for (int i = tid; i < 4096; i += 1024) {
            int k = i >> 6, n = i & 63;
            HiLo h = split2(W[i]);
            sh.lin.wt_hi[n * 72 + k] = h.hi;
            sh.lin.wt_lo[n * 72 + k] = h.lo;
        }
        __syncthreads();

        int wave = tid >> 6, lane = tid & 63;
        int tile = ((int)blockIdx.x - nsc) * 16 + wave;
        if (tile >= ntiles) return;
        int node0 = tile * 16;
        int m = lane & 15;
        int quad = lane >> 4;

        f32x4 acc[4] = {{0.f, 0.f, 0.f, 0.f}, {0.f, 0.f, 0.f, 0.f},
                        {0.f, 0.f, 0.f, 0.f}, {0.f, 0.f, 0.f, 0.f}};

#pragma unroll
        for (int ks = 0; ks < 64; ks += 32) {
            const float* xr = x + (size_t)(node0 + m) * 64 + ks + quad * 8;
            float4 xa = *(const float4*)xr;
            float4 xb = *(const float4*)(xr + 4);
            short8 a_hi, a_lo;
            {
                HiLo h0 = split2(xa.x), h1 = split2(xa.y), h2 = split2(xa.z), h3 = split2(xa.w);
                HiLo h4 = split2(xb.x), h5 = split2(xb.y), h6 = split2(xb.z), h7 = split2(xb.w);
                a_hi[0] = h0.hi; a_lo[0] = h0.lo;  a_hi[1] = h1.hi; a_lo[1] = h1.lo;
                a_hi[2] = h2.hi; a_lo[2] = h2.lo;  a_hi[3] = h3.hi; a_lo[3] = h3.lo;
                a_hi[4] = h4.hi; a_lo[4] = h4.lo;  a_hi[5] = h5.hi; a_lo[5] = h5.lo;
                a_hi[6] = h6.hi; a_lo[6] = h6.lo;  a_hi[7] = h7.hi; a_lo[7] = h7.lo;
            }
#pragma unroll
            for (int g = 0; g < 4; ++g) {
                int n = g * 16 + m;
                int off = n * 72 + ks + quad * 8;
                short8 bh = *(const short8*)&sh.lin.wt_hi[off];
                short8 bl = *(const short8*)&sh.lin.wt_lo[off];
                acc[g] = __builtin_amdgcn_mfma_f32_16x16x32_bf16(a_hi, bh, acc[g], 0, 0, 0);
                acc[g] = __builtin_amdgcn_mfma_f32_16x16x32_bf16(a_lo, bh, acc[g], 0, 0, 0);
                acc[g] = __builtin_amdgcn_mfma_f32_16x16x32_bf16(a_hi, bl, acc[g], 0, 0, 0);
            }
        }

#pragma unroll
        for (int g = 0; g < 4; ++g) {
            float bias = b[g * 16 + m];
#pragma unroll
            for (int r = 0; r < 4; ++r) {
                int node = node0 + quad * 4 + r;
                if (node < N) {
                    float v = acc[g][r] + bias;
                    xl[(size_t)node * 64 + g * 16 + m] = v;
                    xlh[(size_t)node * 64 + g * 16 + m] =
                        (unsigned short)(__float_as_uint(v) >> 16);
                }
            }
        }
    }
}

// ---------------------------------------------------------------------------
// 8-lane partial-dot reduction — DPP only, no DS pipe.
// xor1 = quad_perm [1,0,3,2] (0xB1); xor2 = quad_perm [2,3,0,1] (0x4E);
// xor4 = row_half_mirror (0x141): lane i -> i^7 within 8, which equals the
// other quad's value because the operand is quad-uniform after the first two.
template <int CTRL>
__device__ __forceinline__ float dpp_add(float x) {
    int y = __builtin_amdgcn_update_dpp(0, __float_as_int(x), CTRL, 0xF, 0xF, true);
    return x + __int_as_float(y);
}

__device__ __forceinline__ float red8(float d) {
    d = dpp_add<0xB1>(d);
    d = dpp_add<0x4E>(d);
    d = dpp_add<0x141>(d);
    return d;
}

// unpack 8 bf16 (as uint4) -> two float4 (shift/and only, no cvt)
__device__ __forceinline__ void bf8_to_f8(uint4 u, float4& a, float4& b) {
    a.x = __uint_as_float(u.x << 16);
    a.y = __uint_as_float(u.x & 0xFFFF0000u);
    a.z = __uint_as_float(u.y << 16);
    a.w = __uint_as_float(u.y & 0xFFFF0000u);
    b.x = __uint_as_float(u.z << 16);
    b.y = __uint_as_float(u.z & 0xFFFF0000u);
    b.z = __uint_as_float(u.w << 16);
    b.w = __uint_as_float(u.w & 0xFFFF0000u);
}

__device__ __forceinline__ float dot4(float4 a, float4 b) {
    return a.x * b.x + a.y * b.y + a.z * b.z + a.w * b.w;
}

// branchless edge accumulate: p = exp(score - m_self); self-edges (real or
// pad) masked to 0. Fully uniform, independent FMA chains.
__device__ __forceinline__ void edge_upd(int c, uint4 u, int selfid, float m,
                                         float4 xia, float4 xib,
                                         float& l, float4& A, float4& B) {
    float4 xa, xb;
    bf8_to_f8(u, xa, xb);
    float d = red8(dot4(xia, xa) + dot4(xib, xb));
    d = fmaxf(d, LEAKY_SLOPE * d);       // leaky relu, branchless
    float p = __expf(d - m);
    p = (c != selfid) ? p : 0.0f;        // self handled once at seed
    l += p;
    A.x += p * xa.x; A.y += p * xa.y; A.z += p * xa.z; A.w += p * xa.w;
    B.x += p * xb.x; B.y += p * xb.y; B.z += p * xb.z; B.w += p * xb.w;
}

// ---------------------------------------------------------------------------
// K4 k_agg: per-bucket node-sort (padded to x6) + uniform-slice aggregation.
// 256 threads/block, 32 groups of 8 lanes (lane g = dims [8g,8g+8)).
// Groups round-robin over T = sum(degp)/6 uniform 6-edge slices; per-slice
// partial (l, accA, accB) flushed into LDS accumulators via ds_add_f32.
// Ring-of-6 gathers pipelined across the group's slice stream.
__global__ __launch_bounds__(256) void k_agg(const float* __restrict__ xl,
                                             const unsigned short* __restrict__ xlh,
                                             const unsigned* __restrict__ slab,
                                             const int* __restrict__ base,
                                             float* __restrict__ out, int N) {
    __shared__ int colsh[CAPB];                 // node-sorted + padded edges
    __shared__ float accsh[BK_NODES * 64];      // per-node accumulators (seeded self)
    __shared__ float xish[BK_NODES * 64];       // per-node fp32 xl rows
    __shared__ float lsh[BK_NODES], msh[BK_NODES];
    __shared__ int deg[BK_NODES], degp[BK_NODES], sc[BK_NODES], cur[BK_NODES];
    __shared__ unsigned short slicenode[CAPB / 6];

    int bkt = blockIdx.x;
    int tid = threadIdx.x;
    int grp = tid >> 3;                 // 0..31
    int g = tid & 7;                    // dims [8g, 8g+8)

    int s0 = base[bkt];
    int cnt = base[bkt + 1] - s0;
    if (cnt > CAPB - 5 * BK_NODES) cnt = CAPB - 5 * BK_NODES;  // pad headroom

    if (tid < BK_NODES) { deg[tid] = 0; cur[tid] = 0; }
    __syncthreads();

    // pass 1: degree histogram (slab read #1, sequential, L2-cheap)
    const unsigned* sl = slab + s0;
    for (int i = tid; i < cnt; i += 256)
        atomicAdd(&deg[sl[i] >> 17], 1);
    __syncthreads();

    // lanes 0..31 of wave 0: pad degrees to x6, shfl-scan -> sc (inclusive)
    if (tid < BK_NODES) {
        int d = deg[tid];
        int dp = ((d + 5) / 6) * 6;      // d>=1 (self loop) -> dp>=6; d==0 -> 0
        degp[tid] = dp;
        int v = dp;
#pragma unroll
        for (int o = 1; o < 32; o <<= 1) {
            int t = __shfl_up(v, o, 32);
            if (tid >= o) v += t;
        }
        sc[tid] = v;                     // inclusive scan of PADDED degrees
    }
    __syncthreads();

    // pass 2: node-sorted scatter into padded segments (slab read #2)
    for (int i = tid; i < cnt; i += 256) {
        unsigned pk = sl[i];
        int rl = pk >> 17;
        int p = sc[rl] - degp[rl] + atomicAdd(&cur[rl], 1);
        colsh[p] = (int)(pk & 0x1FFFFu);
    }
    // pad fill + slice->node map
    if (tid < BK_NODES) {
        int b0 = sc[tid] - degp[tid] + deg[tid];
        int b1 = sc[tid];
        int selfid = bkt * BK_NODES + tid;
        for (int i = b0; i < b1; ++i) colsh[i] = selfid;
        int t0 = (sc[tid] - degp[tid]) / 6;
        int nt = degp[tid] / 6;
        for (int k = 0; k < nt; ++k) slicenode[t0 + k] = (unsigned short)tid;
    }
    // seed: xish = fp32 row, accsh = self contribution (p=1), m = ||xi||^2
    {
        int node = bkt * BK_NODES + grp;
        float4 xia = {0.f, 0.f, 0.f, 0.f}, xib = {0.f, 0.f, 0.f, 0.f};
        if (node < N) {
            xia = ((const float4*)xl)[(size_t)node * 16 + 2 * g];
            xib = ((const float4*)xl)[(size_t)node * 16 + 2 * g + 1];
        }
        *(float4*)&xish[grp * 64 + 8 * g]     = xia;
        *(float4*)&xish[grp * 64 + 8 * g + 4] = xib;
        *(float4*)&accsh[grp * 64 + 8 * g]     = xia;
        *(float4*)&accsh[grp * 64 + 8 * g + 4] = xib;
        float mv = red8(dot4(xia, xia) + dot4(xib, xib));
        if (g == 0) { msh[grp] = mv; lsh[grp] = 1.0f; }
    }
    __syncthreads();

    int T = sc[BK_NODES - 1] / 6;       // total 6-edge slices
    const uint4* xh4 = (const uint4*)xlh;

    if (grp < T) {
        int t = grp;
        // ring preload: slice t's 6 edges
        int c0 = colsh[6 * t + 0], c1 = colsh[6 * t + 1], c2 = colsh[6 * t + 2];
        int c3 = colsh[6 * t + 3], c4 = colsh[6 * t + 4], c5 = colsh[6 * t + 5];
        uint4 u0 = xh4[(unsigned)(c0 * 8 + g)];
        uint4 u1 = xh4[(unsigned)(c1 * 8 + g)];
        uint4 u2 = xh4[(unsigned)(c2 * 8 + g)];
        uint4 u3 = xh4[(unsigned)(c3 * 8 + g)];
        uint4 u4 = xh4[(unsigned)(c4 * 8 + g)];
        uint4 u5 = xh4[(unsigned)(c5 * 8 + g)];

        while (t < T) {
            int n = slicenode[t];
            float mv = msh[n];
            int selfid = bkt * BK_NODES + n;
            float4 xia = *(const float4*)&xish[n * 64 + 8 * g];
            float4 xib = *(const float4*)&xish[n * 64 + 8 * g + 4];
            float lp = 0.f;
            float4 pA = {0.f, 0.f, 0.f, 0.f}, pB = {0.f, 0.f, 0.f, 0.f};

            int tn = t + 32;
            int tl = (tn < T) ? tn : t;  // clamp: garbage refill never consumed
            int eb = 6 * tl;

            // consume slot i, refill slot i from the group's next slice
            edge_upd(c0, u0, selfid, mv, xia, xib, lp, pA, pB);
            c0 = colsh[eb + 0]; u0 = xh4[(unsigned)(c0 * 8 + g)];
            edge_upd(c1, u1, selfid, mv, xia, xib, lp, pA, pB);
            c1 = colsh[eb + 1]; u1 = xh4[(unsigned)(c1 * 8 + g)];
            edge_upd(c2, u2, selfid, mv, xia, xib, lp, pA, pB);
            c2 = colsh[eb + 2]; u2 = xh4[(unsigned)(c2 * 8 + g)];
            edge_upd(c3, u3, selfid, mv, xia, xib, lp, pA, pB);
            c3 = colsh[eb + 3]; u3 = xh4[(unsigned)(c3 * 8 + g)];
            edge_upd(c4, u4, selfid, mv, xia, xib, lp, pA, pB);
            c4 = colsh[eb + 4]; u4 = xh4[(unsigned)(c4 * 8 + g)];
            edge_upd(c5, u5, selfid, mv, xia, xib, lp, pA, pB);
            c5 = colsh[eb + 5]; u5 = xh4[(unsigned)(c5 * 8 + g)];

            // flush partials (fixed-m partial sums are addable)
            float* an = &accsh[n * 64 + 8 * g];
            atomicAdd(&an[0], pA.x); atomicAdd(&an[1], pA.y);
            atomicAdd(&an[2], pA.z); atomicAdd(&an[3], pA.w);
            atomicAdd(&an[4], pB.x); atomicAdd(&an[5], pB.y);
            atomicAdd(&an[6], pB.z); atomicAdd(&an[7], pB.w);
            if (g == 0) atomicAdd(&lsh[n], lp);

            t = tn;
        }
    }
    __syncthreads();

    // output: group grp handles node grp
    {
        int node = bkt * BK_NODES + grp;
        if (node < N) {
            float inv = 1.0f / lsh[grp];       // l >= 1 (self term)
            float4 oA = *(float4*)&accsh[grp * 64 + 8 * g];
            float4 oB = *(float4*)&accsh[grp * 64 + 8 * g + 4];
            oA.x *= inv; oA.y *= inv; oA.z *= inv; oA.w *= inv;
            oB.x *= inv; oB.y *= inv; oB.z *= inv; oB.w *= inv;
            ((float4*)out)[(size_t)node * 16 + 2 * g] = oA;
            ((float4*)out)[(size_t)node * 16 + 2 * g + 1] = oB;
        }
    }
}

// ---------------------------------------------------------------------------
extern "C" void kernel_launch(void* const* d_in, const int* in_sizes, int n_in,
                              void* d_out, int out_size, void* d_ws, size_t ws_size,
                              hipStream_t stream) {
    const float* x = (const float*)d_in[0];
    const int* ei = (const int*)d_in[1];
    const float* W = (const float*)d_in[2];
    const float* b = (const float*)d_in[3];

    const int N = in_sizes[0] / 64;            // 100000
    const int E = in_sizes[1] / 2;             // 1700000
    const int NO = N * 64;
    const int NB = (N + BK_NODES - 1) >> BK_SHIFT;   // 3125
    const int NCH = (E + CH - 1) / CH;         // 208
    const int* row = ei;                       // destination (edge_index[0])
    const int* col = ei + E;                   // source      (edge_index[1])

    float* out = (float*)d_out;

    float* ws = (float*)d_ws;
    float* xl           = ws;                                   // N*64 f32
    unsigned short* xlh = (unsigned short*)(xl + (size_t)NO);   // N*64 bf16
    unsigned short* cntg= xlh + (size_t)NO;                     // NCH*NBP u16
    int* tot            = (int*)(cntg + (size_t)NCH * NBP);     // NB i32
    int* base           = tot + NB;                             // NB+1 i32
    unsigned* slab      = (unsigned*)(base + NB + 1);           // E u32

    const int ntiles = (N + 15) / 16;          // 6250
    const int lblocks = (ntiles + 15) / 16;    // 391 (16 tiles/block)

    k_hist<<<NCH, 1024, 0, stream>>>(row, cntg, E, NB);
    k_tot<<<(NB + 3) / 4, 256, 0, stream>>>(cntg, tot, NB, NCH);
    k_base<<<1, 1024, 0, stream>>>(tot, base, NB, E);
    k_scatlin<<<NCH + lblocks, 1024, 0, stream>>>(x, W, b, row, col, xl, xlh,
                                                  cntg, base, slab,
                                                  N, E, NB, ntiles, NCH, NCH);
    k_agg<<<NB, 256, 0, stream>>>(xl, xlh, slab, base, out, N);
}

// Round 10
// 164.082 us; speedup vs baseline: 1.5892x; 1.5892x over previous
//
#include <hip/hip_runtime.h>
#include <hip/hip_bf16.h>

// GATConv forward, eval mode.
// Inputs: x[N,64] fp32, edge_index[2,E] int32, W[64,64] fp32, b[64] fp32.
// Output: fp32 [N,64].
//
// Pipeline (4 kernels, no memset):
//   K0 k_hist   : per 8192-edge chunk LDS bucket histogram (3125 buckets of
//                 32 nodes) -> cntg[chunk][bkt] u16.
//   K1 k_tot    : one wave per bucket: lane l serial-prefixes chunks
//                 [4l,4l+4), shfl-scan across lanes, per-chunk prefix in
//                 place, bucket total -> tot[]. (Global base scan DELETED:
//                 each bucket owns a fixed 768-entry slab region, so the
//                 round-9 k_base kernel + launch gap are gone.)
//   K2 k_scatlin: blocks [0,NCH): scatter each edge to its final slab slot
//                 bkt*768 + cntg[chunk][bkt] + rank (LDS rank counters only);
//                 consecutive chunks pinned to one XCD (avoids round-4's
//                 cross-XCD line ping-pong: 128MB WRITE for an 8.4MB slab).
//                 blocks [NCH,...): xl = x@W+b via MFMA bf16x2 split (+ bf16
//                 xlh), 16 tiles/block — linear is off the partition critical
//                 path, so it overlaps the scatter phase.
//   K3 k_agg    : per bucket (3125 blocks): contiguous slab-region read, LDS
//                 node-sort with per-node padding to a multiple of 6 using
//                 dummy self-edges (fixed-m softmax makes them exact zeros),
//                 degree-rank order, RING-OF-6 software-pipelined per-node
//                 gather loop (round 9 proved slice-balancing regresses 3x:
//                 per-slice LDS xi/m reads + 8-way-conflicting LDS atomic
//                 flushes sit on the latency-critical path; per-node keeps
//                 xi/m/acc in registers). Softmax BRANCHLESS: m fixed to the
//                 self score ||xl_i||^2 (Cauchy-Schwarz bounds exp<=e^~30),
//                 self seeded in fp32. 8-lane dot reduce is DPP-only.
//                 Plain __launch_bounds__(256): round 7 proved (256,8)
//                 [min waves/EU] caps VGPR=32 and spills the ring (343MB
//                 scratch traffic, 160us).
//
// ws: xl[N*64] f32 | xlh[N*64] bf16 | cntg[NCH*NBP] u16 | tot[NB] i32 |
//     slab[NB*SLABW] u32

#define LEAKY_SLOPE 0.2f
#define BK_SHIFT 5            // 32 nodes per bucket
#define BK_NODES 32
#define SLABW 768             // fixed slab region per bucket (mean 544, ~10 sigma)
#define CAPB 960              // LDS bound on PADDED edges/bucket (768 + 5*32)
#define CH 8192               // edges per chunk
#define NBP 3136              // padded bucket count (NB=3125)
#define MAXK 8                // max chunks per lane in k_tot (need ceil(208/64)=4)

typedef __attribute__((ext_vector_type(8))) short short8;   // 8 x bf16 bits
typedef __attribute__((ext_vector_type(4))) float f32x4;

struct HiLo { short hi, lo; };

__device__ __forceinline__ HiLo split2(float f) {
    HiLo r;
    unsigned u = __float_as_uint(f);
    r.hi = (short)(u >> 16);
    float fh = __uint_as_float(u & 0xFFFF0000u);
    r.lo = (short)(__float_as_uint(f - fh) >> 16);
    return r;
}

// ---------------------------------------------------------------------------
// K0 k_hist: per-chunk bucket histogram -> cntg[chunk][bkt] (u16)
__global__ __launch_bounds__(1024) void k_hist(const int* __restrict__ row,
                                               unsigned short* __restrict__ cntg,
                                               int E, int NB) {
    __shared__ int hc[NBP];
    int tid = threadIdx.x;
    for (int i = tid; i < NBP; i += 1024) hc[i] = 0;
    __syncthreads();
    int e0 = (int)blockIdx.x * CH;
    int e1 = min(E, e0 + CH);
    for (int e = e0 + tid; e < e1; e += 1024)
        atomicAdd(&hc[row[e] >> BK_SHIFT], 1);
    __syncthreads();
    unsigned short* orow = cntg + (size_t)blockIdx.x * NBP;
    for (int i = tid; i < NB; i += 1024) orow[i] = (unsigned short)hc[i];
}

// ---------------------------------------------------------------------------
// K1 k_tot: one wave per bucket. Lane l serial-prefixes its 4 contiguous
// chunks, shfl-scan combines lanes, prefix written back in place, total out.
__global__ __launch_bounds__(256) void k_tot(unsigned short* __restrict__ cntg,
                                             int* __restrict__ tot,
                                             int NB, int nch) {
    int wavegid = (((int)blockIdx.x * 256) + (int)threadIdx.x) >> 6;
    int lane = threadIdx.x & 63;
    int b = wavegid;                     // bucket handled by this wave
    if (b >= NB) return;                 // wave-uniform exit

    int K = (nch + 63) >> 6;             // chunks per lane (4 for nch=208)
    int v[MAXK];
    int s = 0;
    int c0 = lane * K;
#pragma unroll
    for (int k = 0; k < MAXK; ++k) {
        if (k < K) {
            int c = c0 + k;
            v[k] = (c < nch) ? (int)cntg[(size_t)c * NBP + b] : 0;
        }
    }
#pragma unroll
    for (int k = 0; k < MAXK; ++k) {
        if (k < K) { int t = v[k]; v[k] = s; s += t; }
    }
    int inc = s;                         // inclusive scan of lane sums
#pragma unroll
    for (int o = 1; o < 64; o <<= 1) {
        int t = __shfl_up(inc, o, 64);
        if (lane >= o) inc += t;
    }
    int exc = inc - s;                   // exclusive prefix for this lane
#pragma unroll
    for (int k = 0; k < MAXK; ++k) {
        if (k < K) {
            int c = c0 + k;
            if (c < nch)
                cntg[(size_t)c * NBP + b] = (unsigned short)(v[k] + exc);
        }
    }
    if (lane == 63) tot[b] = inc;
}

// ---------------------------------------------------------------------------
// K2 k_scatlin: scatter (blocks [0,nsc)) + linear MFMA (blocks after).
union SLShMem {
    struct { short wt_hi[64 * 72]; short wt_lo[64 * 72]; } lin;   // 18432 B
    struct { int pfx[NBP], pos[NBP]; } sc;                        // 25088 B
};

__global__ __launch_bounds__(1024) void k_scatlin(const float* __restrict__ x,
                                                  const float* __restrict__ W,
                                                  const float* __restrict__ b,
                                                  const int* __restrict__ row,
                                                  const int* __restrict__ col,
                                                  float* __restrict__ xl,
                                                  unsigned short* __restrict__ xlh,
                                                  const unsigned short* __restrict__ cntg,
                                                  unsigned* __restrict__ slab,
                                                  int N, int E, int NB,
                                                  int ntiles, int nsc, int nch) {
    __shared__ SLShMem sh;
    int tid = threadIdx.x;

    if ((int)blockIdx.x < nsc) {
        // ---------------------- scatter path -------------------------------
        int cb = (int)blockIdx.x;
        // consecutive chunks on the same XCD (round-robin heuristic): keeps
        // adjacent runs of each bucket region in one XCD's L2.
        int chunk = (nch % 8 == 0) ? (cb % 8) * (nch / 8) + cb / 8 : cb;

        const unsigned short* crow = cntg + (size_t)chunk * NBP;
        for (int i = tid; i < NB; i += 1024) {
            sh.sc.pfx[i] = i * SLABW + (int)crow[i];   // fixed region per bucket
            sh.sc.pos[i] = 0;
        }
        __syncthreads();

        int e0 = chunk * CH;
        int e1 = min(E, e0 + CH);
        for (int e = e0 + tid; e < e1; e += 1024) {
            int r = row[e], c = col[e];
            int bkt = r >> BK_SHIFT;
            int rank = atomicAdd(&sh.sc.pos[bkt], 1);
            int p = sh.sc.pfx[bkt] + rank;
            if (p < (bkt + 1) * SLABW)                 // region overflow guard
                slab[p] = ((unsigned)(r & (BK_NODES - 1)) << 17) | (unsigned)c;
        }
    } else {
        // ------------------------- linear path (MFMA) ----------------------
        for (int i = tid; i < 4096; i += 1024) {
            int k = i >> 6, n = i & 63;
            HiLo h = split2(W[i]);
            sh.lin.wt_hi[n * 72 + k] = h.hi;
            sh.lin.wt_lo[n * 72 + k] = h.lo;
        }
        __syncthreads();

        int wave = tid >> 6, lane = tid & 63;
        int tile = ((int)blockIdx.x - nsc) * 16 + wave;
        if (tile >= ntiles) return;
        int node0 = tile * 16;
        int m = lane & 15;
        int quad = lane >> 4;

        f32x4 acc[4] = {{0.f, 0.f, 0.f, 0.f}, {0.f, 0.f, 0.f, 0.f},
                        {0.f, 0.f, 0.f, 0.f}, {0.f, 0.f, 0.f, 0.f}};

#pragma unroll
        for (int ks = 0; ks < 64; ks += 32) {
            const float* xr = x + (size_t)(node0 + m) * 64 + ks + quad * 8;
            float4 xa = *(const float4*)xr;
            float4 xb = *(const float4*)(xr + 4);
            short8 a_hi, a_lo;
            {
                HiLo h0 = split2(xa.x), h1 = split2(xa.y), h2 = split2(xa.z), h3 = split2(xa.w);
                HiLo h4 = split2(xb.x), h5 = split2(xb.y), h6 = split2(xb.z), h7 = split2(xb.w);
                a_hi[0] = h0.hi; a_lo[0] = h0.lo;  a_hi[1] = h1.hi; a_lo[1] = h1.lo;
                a_hi[2] = h2.hi; a_lo[2] = h2.lo;  a_hi[3] = h3.hi; a_lo[3] = h3.lo;
                a_hi[4] = h4.hi; a_lo[4] = h4.lo;  a_hi[5] = h5.hi; a_lo[5] = h5.lo;
                a_hi[6] = h6.hi; a_lo[6] = h6.lo;  a_hi[7] = h7.hi; a_lo[7] = h7.lo;
            }
#pragma unroll
            for (int g = 0; g < 4; ++g) {
                int n = g * 16 + m;
                int off = n * 72 + ks + quad * 8;
                short8 bh = *(const short8*)&sh.lin.wt_hi[off];
                short8 bl = *(const short8*)&sh.lin.wt_lo[off];
                acc[g] = __builtin_amdgcn_mfma_f32_16x16x32_bf16(a_hi, bh, acc[g], 0, 0, 0);
                acc[g] = __builtin_amdgcn_mfma_f32_16x16x32_bf16(a_lo, bh, acc[g], 0, 0, 0);
                acc[g] = __builtin_amdgcn_mfma_f32_16x16x32_bf16(a_hi, bl, acc[g], 0, 0, 0);
            }
        }

#pragma unroll
        for (int g = 0; g < 4; ++g) {
            float bias = b[g * 16 + m];
#pragma unroll
            for (int r = 0; r < 4; ++r) {
                int node = node0 + quad * 4 + r;
                if (node < N) {
                    float v = acc[g][r] + bias;
                    xl[(size_t)node * 64 + g * 16 + m] = v;
                    xlh[(size_t)node * 64 + g * 16 + m] =
                        (unsigned short)(__float_as_uint(v) >> 16);
                }
            }
        }
    }
}

// ---------------------------------------------------------------------------
// 8-lane partial-dot reduction — DPP only, no DS pipe.
// xor1 = quad_perm [1,0,3,2] (0xB1); xor2 = quad_perm [2,3,0,1] (0x4E);
// xor4 = row_half_mirror (0x141): lane i -> i^7 within 8, which equals the
// other quad's value because the operand is quad-uniform after the first two.
template <int CTRL>
__device__ __forceinline__ float dpp_add(float x) {
    int y = __builtin_amdgcn_update_dpp(0, __float_as_int(x), CTRL, 0xF, 0xF, true);
    return x + __int_as_float(y);
}

__device__ __forceinline__ float red8(float d) {
    d = dpp_add<0xB1>(d);
    d = dpp_add<0x4E>(d);
    d = dpp_add<0x141>(d);
    return d;
}

// unpack 8 bf16 (as uint4) -> two float4 (shift/and only, no cvt)
__device__ __forceinline__ void bf8_to_f8(uint4 u, float4& a, float4& b) {
    a.x = __uint_as_float(u.x << 16);
    a.y = __uint_as_float(u.x & 0xFFFF0000u);
    a.z = __uint_as_float(u.y << 16);
    a.w = __uint_as_float(u.y & 0xFFFF0000u);
    b.x = __uint_as_float(u.z << 16);
    b.y = __uint_as_float(u.z & 0xFFFF0000u);
    b.z = __uint_as_float(u.w << 16);
    b.w = __uint_as_float(u.w & 0xFFFF0000u);
}

__device__ __forceinline__ float dot4(float4 a, float4 b) {
    return a.x * b.x + a.y * b.y + a.z * b.z + a.w * b.w;
}

// branchless edge accumulate: p = exp(score - m_self); self-edges (real or
// pad) masked to 0. Fully uniform, independent FMA chains.
__device__ __forceinline__ void edge_upd(int c, uint4 u, int node, float m,
                                         float4 xia, float4 xib,
                                         float& l, float4& A, float4& B) {
    float4 xa, xb;
    bf8_to_f8(u, xa, xb);
    float d = red8(dot4(xia, xa) + dot4(xib, xb));
    d = fmaxf(d, LEAKY_SLOPE * d);       // leaky relu, branchless
    float p = __expf(d - m);
    p = (c != node) ? p : 0.0f;          // self handled once in fp32 at init
    l += p;
    A.x += p * xa.x; A.y += p * xa.y; A.z += p * xa.z; A.w += p * xa.w;
    B.x += p * xb.x; B.y += p * xb.y; B.z += p * xb.z; B.w += p * xb.w;
}

// ---------------------------------------------------------------------------
// K3 k_agg: per-bucket slab-region read + LDS node-sort (padded to x6 with
// dummy self-edges) + ring-of-6 pipelined fused softmax. 256 threads/block,
// 32 groups of 8 lanes (group = one node, lane g = dims [8g,8g+8)),
// degree-rank-sorted node order.
__global__ __launch_bounds__(256) void k_agg(const float* __restrict__ xl,
                                             const unsigned short* __restrict__ xlh,
                                             const unsigned* __restrict__ slab,
                                             const int* __restrict__ tot,
                                             float* __restrict__ out, int N) {
    __shared__ int raw[SLABW];          // bucket edges, slab order
    __shared__ int colsh[CAPB];         // bucket edges, node-sorted + padded
    __shared__ int deg[BK_NODES], degp[BK_NODES], sc[BK_NODES];
    __shared__ int cur[BK_NODES], ord[BK_NODES];

    int bkt = blockIdx.x;
    int tid = threadIdx.x;

    int cnt = tot[bkt];
    if (cnt > SLABW) cnt = SLABW;

    if (tid < BK_NODES) { deg[tid] = 0; cur[tid] = 0; }
    __syncthreads();

    // contiguous slab-region read + LDS degree histogram
    const unsigned* sl = slab + (size_t)bkt * SLABW;
    for (int i = tid; i < cnt; i += 256) {
        int e = (int)sl[i];
        raw[i] = e;
        atomicAdd(&deg[((unsigned)e) >> 17], 1);
    }
    __syncthreads();

    // lanes 0..31 of wave 0: pad degrees to multiple of 6, shfl-scan of
    // padded deg -> sc (inclusive), plus degree-rank order.
    if (tid < BK_NODES) {
        int d = deg[tid];
        int dp = ((d + 5) / 6) * 6;      // d >= 1 (self loop) -> dp >= 6
        degp[tid] = dp;
        int v = dp;
#pragma unroll
        for (int o = 1; o < 32; o <<= 1) {
            int t = __shfl_up(v, o, 32);
            if (tid >= o) v += t;
        }
        sc[tid] = v;                     // inclusive scan of PADDED degrees
        int r = 0;
#pragma unroll
        for (int j = 0; j < BK_NODES; ++j) {
            int dj = deg[j];
            r += (dj > d) || (dj == d && j < tid);
        }
        ord[r] = tid;                    // rank r (desc degree) -> node n0
    }
    __syncthreads();

    // node-sorted scatter into padded segments
    for (int i = tid; i < cnt; i += 256) {
        unsigned pk = (unsigned)raw[i];
        int rl = pk >> 17;
        int p = sc[rl] - degp[rl] + atomicAdd(&cur[rl], 1);
        colsh[p] = (int)(pk & 0x1FFFFu);
    }
    // fill pad slots with self id (exact zeros in the fixed-m softmax)
    if (tid < BK_NODES) {
        int b0 = sc[tid] - degp[tid] + deg[tid];
        int b1 = sc[tid];
        int selfid = bkt * BK_NODES + tid;
        for (int i = b0; i < b1; ++i) colsh[i] = selfid;
    }
    __syncthreads();

    int grp = tid >> 3;                 // 0..31 -> exactly one node each
    int g = tid & 7;                    // dims [8g, 8g+8)
    const uint4* xh4 = (const uint4*)xlh;
    int n0 = ord[grp];                  // degree-rank ordered
    int node = bkt * BK_NODES + n0;
    if (node < N) {
        int e = sc[n0] - degp[n0];
        int end = sc[n0];               // end - e is a multiple of 6, >= 6
        float4 xia = ((const float4*)xl)[(size_t)node * 16 + 2 * g];
        float4 xib = ((const float4*)xl)[(size_t)node * 16 + 2 * g + 1];

        // fixed softmax shift m = self score ||xl_i||^2 (>=0, leaky no-op);
        // seed self contribution (p=1) with fp32 row.
        float mval = red8(dot4(xia, xia) + dot4(xib, xib));
        float l = 1.0f;
        float4 accA = xia;
        float4 accB = xib;

        // ring-of-6: prologue loads edges e..e+5
        int c0 = colsh[e],     c1 = colsh[e + 1], c2 = colsh[e + 2];
        int c3 = colsh[e + 3], c4 = colsh[e + 4], c5 = colsh[e + 5];
        uint4 u0 = xh4[(unsigned)(c0 * 8 + g)];
        uint4 u1 = xh4[(unsigned)(c1 * 8 + g)];
        uint4 u2 = xh4[(unsigned)(c2 * 8 + g)];
        uint4 u3 = xh4[(unsigned)(c3 * 8 + g)];
        uint4 u4 = xh4[(unsigned)(c4 * 8 + g)];
        uint4 u5 = xh4[(unsigned)(c5 * 8 + g)];

        // steady state: consume slot i, immediately re-issue it for e+6+i —
        // each gather is in flight ~6 edge-computes before its use.
        for (; e + 12 <= end; e += 6) {
            edge_upd(c0, u0, node, mval, xia, xib, l, accA, accB);
            c0 = colsh[e + 6];  u0 = xh4[(unsigned)(c0 * 8 + g)];
            edge_upd(c1, u1, node, mval, xia, xib, l, accA, accB);
            c1 = colsh[e + 7];  u1 = xh4[(unsigned)(c1 * 8 + g)];
            edge_upd(c2, u2, node, mval, xia, xib, l, accA, accB);
            c2 = colsh[e + 8];  u2 = xh4[(unsigned)(c2 * 8 + g)];
            edge_upd(c3, u3, node, mval, xia, xib, l, accA, accB);
            c3 = colsh[e + 9];  u3 = xh4[(unsigned)(c3 * 8 + g)];
            edge_upd(c4, u4, node, mval, xia, xib, l, accA, accB);
            c4 = colsh[e + 10]; u4 = xh4[(unsigned)(c4 * 8 + g)];
            edge_upd(c5, u5, node, mval, xia, xib, l, accA, accB);
            c5 = colsh[e + 11]; u5 = xh4[(unsigned)(c5 * 8 + g)];
        }
        // epilogue: exactly the final 6 (loaded by prologue or last iter)
        edge_upd(c0, u0, node, mval, xia, xib, l, accA, accB);
        edge_upd(c1, u1, node, mval, xia, xib, l, accA, accB);
        edge_upd(c2, u2, node, mval, xia, xib, l, accA, accB);
        edge_upd(c3, u3, node, mval, xia, xib, l, accA, accB);
        edge_upd(c4, u4, node, mval, xia, xib, l, accA, accB);
        edge_upd(c5, u5, node, mval, xia, xib, l, accA, accB);

        float inv = 1.0f / l;            // l >= 1 (self term)
        float4 oA = {accA.x * inv, accA.y * inv, accA.z * inv, accA.w * inv};
        float4 oB = {accB.x * inv, accB.y * inv, accB.z * inv, accB.w * inv};
        ((float4*)out)[(size_t)node * 16 + 2 * g] = oA;
        ((float4*)out)[(size_t)node * 16 + 2 * g + 1] = oB;
    }
}

// ---------------------------------------------------------------------------
extern "C" void kernel_launch(void* const* d_in, const int* in_sizes, int n_in,
                              void* d_out, int out_size, void* d_ws, size_t ws_size,
                              hipStream_t stream) {
    const float* x = (const float*)d_in[0];
    const int* ei = (const int*)d_in[1];
    const float* W = (const float*)d_in[2];
    const float* b = (const float*)d_in[3];

    const int N = in_sizes[0] / 64;            // 100000
    const int E = in_sizes[1] / 2;             // 1700000
    const int NO = N * 64;
    const int NB = (N + BK_NODES - 1) >> BK_SHIFT;   // 3125
    const int NCH = (E + CH - 1) / CH;         // 208
    const int* row = ei;                       // destination (edge_index[0])
    const int* col = ei + E;                   // source      (edge_index[1])

    float* out = (float*)d_out;

    float* ws = (float*)d_ws;
    float* xl           = ws;                                   // N*64 f32
    unsigned short* xlh = (unsigned short*)(xl + (size_t)NO);   // N*64 bf16
    unsigned short* cntg= xlh + (size_t)NO;                     // NCH*NBP u16
    int* tot            = (int*)(cntg + (size_t)NCH * NBP);     // NB i32
    unsigned* slab      = (unsigned*)(tot + NB);                // NB*SLABW u32

    const int ntiles = (N + 15) / 16;          // 6250
    const int lblocks = (ntiles + 15) / 16;    // 391 (16 tiles/block)

    k_hist<<<NCH, 1024, 0, stream>>>(row, cntg, E, NB);
    k_tot<<<(NB + 3) / 4, 256, 0, stream>>>(cntg, tot, NB, NCH);
    k_scatlin<<<NCH + lblocks, 1024, 0, stream>>>(x, W, b, row, col, xl, xlh,
                                                  cntg, slab,
                                                  N, E, NB, ntiles, NCH, NCH);
    k_agg<<<NB, 256, 0, stream>>>(xl, xlh, slab, tot, out, N);
}